// Round 11
// baseline (207.049 us; speedup 1.0000x reference)
//
#include <hip/hip_runtime.h>
#include <hip/hip_bf16.h>
#include <cstdint>

#define TT   8192
#define KOBS 512
#define HID  2048
#define NOBJ 8
#define NCH  64     // number of scan chunks (= gemm t-tiles)
#define CT   128    // chunk length (TT / NCH)

typedef unsigned short u16;
typedef uint32_t u32;
typedef short bf16x8 __attribute__((ext_vector_type(8)));
typedef float f32x4  __attribute__((ext_vector_type(4)));
typedef unsigned short u16x4 __attribute__((ext_vector_type(4)));
typedef unsigned short u16x8 __attribute__((ext_vector_type(8)));

static __device__ __forceinline__ float bf2f(u16 u) {
    union { uint32_t i; float f; } v;
    v.i = ((uint32_t)u) << 16;
    return v.f;
}
static __device__ __forceinline__ u16 f2bf(float f) {
    union { float f; uint32_t i; } v;
    v.f = f;
    uint32_t lsb = (v.i >> 16) & 1u;
    uint32_t r = v.i + 0x7fffu + lsb;   // round-to-nearest-even
    return (u16)(r >> 16);
}

// async global->LDS DMA, 16 bytes per lane (wave-uniform base + lane*16).
static __device__ __forceinline__ void async_ld16(const u16* g, u16* l) {
    __builtin_amdgcn_global_load_lds(
        (const __attribute__((address_space(1))) uint32_t*)g,
        (__attribute__((address_space(3))) uint32_t*)l,
        16, 0, 0);
}

// ---------------------------------------------------------------------------
// Kernel 1 (merged prep):
//  blocks [0,512):    out base = b_out + x @ W_skip.T; x -> bf16 cast
//  blocks [512,1536): W cast + row-interleave (row n = 4h+proj); A_e
// ---------------------------------------------------------------------------
__launch_bounds__(256)
__global__ void prep_all(const float* __restrict__ x,
                         const float* __restrict__ Win,
                         const float* __restrict__ WB,
                         const float* __restrict__ WC,
                         const float* __restrict__ Wd,
                         const float* __restrict__ A_log,
                         const float* __restrict__ b_out,
                         const float* __restrict__ W_skip,
                         float* __restrict__ out,
                         u16* __restrict__ x_bf,
                         u16* __restrict__ W_bf,
                         float* __restrict__ A_e)
{
    if (blockIdx.x < 512) {
        const int wave = threadIdx.x >> 6;
        const int lane = threadIdx.x & 63;
        const int t0 = (blockIdx.x * 4 + wave) * 4;

        float acc[4][NOBJ];
#pragma unroll
        for (int tt = 0; tt < 4; tt++)
#pragma unroll
            for (int o = 0; o < NOBJ; o++) acc[tt][o] = 0.f;

#pragma unroll
        for (int i = 0; i < 2; i++) {
            const int kv = (i * 64 + lane) * 4;
            float4 w[NOBJ];
#pragma unroll
            for (int o = 0; o < NOBJ; o++)
                w[o] = *(const float4*)(W_skip + (size_t)o * KOBS + kv);
#pragma unroll
            for (int tt = 0; tt < 4; tt++) {
                const size_t off = (size_t)(t0 + tt) * KOBS + kv;
                float4 xv = *(const float4*)(x + off);
                u16x4 xb = { f2bf(xv.x), f2bf(xv.y), f2bf(xv.z), f2bf(xv.w) };
                *(u16x4*)&x_bf[off] = xb;
#pragma unroll
                for (int o = 0; o < NOBJ; o++)
                    acc[tt][o] += xv.x * w[o].x + xv.y * w[o].y +
                                  xv.z * w[o].z + xv.w * w[o].w;
            }
        }
#pragma unroll
        for (int s = 32; s > 0; s >>= 1)
#pragma unroll
            for (int tt = 0; tt < 4; tt++)
#pragma unroll
                for (int o = 0; o < NOBJ; o++)
                    acc[tt][o] += __shfl_xor(acc[tt][o], s, 64);
        if (lane == 0) {
#pragma unroll
            for (int tt = 0; tt < 4; tt++)
#pragma unroll
                for (int o = 0; o < NOBJ; o++)
                    out[(size_t)(t0 + tt) * NOBJ + o] = acc[tt][o] + b_out[o];
        }
    } else {
        const int tid0 = (blockIdx.x - 512) * 256 + threadIdx.x; // 0..262143
#pragma unroll
        for (int q = 0; q < 2; q++) {
            const int i = tid0 + q * 262144;     // group of 8 elems
            int n  = i >> 6;
            int k8 = (i & 63) * 8;
            int h  = n >> 2;
            int w  = n & 3;
            const float* src = (w == 0) ? Win : (w == 1) ? WB
                             : (w == 2) ? WC  : Wd;
            const float4* s4 = (const float4*)(src + (size_t)h * KOBS + k8);
            float4 a = s4[0], b = s4[1];
            u16x4 o1 = { f2bf(a.x), f2bf(a.y), f2bf(a.z), f2bf(a.w) };
            u16x4 o2 = { f2bf(b.x), f2bf(b.y), f2bf(b.z), f2bf(b.w) };
            *(u16x4*)&W_bf[(size_t)i * 8]     = o1;
            *(u16x4*)&W_bf[(size_t)i * 8 + 4] = o2;
        }
        if (tid0 < HID)
            A_e[tid0] = -__expf(A_log[tid0]) * 1.44269504f;
    }
}

// ---------------------------------------------------------------------------
// Kernel 2: fused GEMM + elementwise + in-LDS chunk scan + YB projection
// (bf16 partial stores, NO atomics; occupancy pinned by launch_bounds(256,6)).
// ---------------------------------------------------------------------------
__launch_bounds__(256, 6)
__global__ void gemm_fused(const u16* __restrict__ x_bf,
                           const u16* __restrict__ W_bf,
                           const float* __restrict__ A_e,
                           const float* __restrict__ W_out,
                           u16* __restrict__ YC,
                           u16* __restrict__ Ptl16,
                           float* __restrict__ P,
                           float* __restrict__ S)
{
    __shared__ __align__(16) u16 smem[3 * 128 * 40];   // 30720 B
    __shared__ float Ps[256], Ss[256];                 //  2 KB
    u16* a_s = smem;            // x tile: 128 t-rows x 32 k
    u16* b_s = smem + 4096;     // W tile: 128 n-rows x 32 k

    const int tid  = threadIdx.x;
    const int bm   = blockIdx.x & 63;    // t-chunk (== scan chunk c)
    const int bn   = blockIdx.x >> 6;    // channel group (32 h)
    const int m0t  = bm * 128;
    const int n0   = bn * 128;
    const int lane = tid & 63;
    const int wave = tid >> 6;
    const int wn   = (wave & 1) * 64;    // n-dim wave offset
    const int wt   = (wave >> 1) * 64;   // t-dim wave offset
    const int fr   = lane & 15;
    const int fq   = lane >> 4;

    f32x4 acc[4][4];
#pragma unroll
    for (int i = 0; i < 4; i++)
#pragma unroll
        for (int j = 0; j < 4; j++) {
            f32x4 z = {0.f, 0.f, 0.f, 0.f};
            acc[i][j] = z;
        }

    const int srow = tid >> 2;                       // 0..63
    const int scg  = (tid & 3) ^ ((srow >> 1) & 3);  // XOR col-group swizzle
    const u16* gA0 = x_bf + (size_t)(m0t + srow) * KOBS + scg * 8;
    const u16* gA1 = gA0 + (size_t)64 * KOBS;
    const u16* gB0 = W_bf + (size_t)(n0 + srow) * KOBS + scg * 8;
    const u16* gB1 = gB0 + (size_t)64 * KOBS;
    u16* lA0 = &a_s[tid * 8];
    u16* lA1 = &a_s[2048 + tid * 8];
    u16* lB0 = &b_s[tid * 8];
    u16* lB1 = &b_s[2048 + tid * 8];

    const int pcg = fq ^ ((fr >> 1) & 3);  // fragment-read swizzled col-group

    for (int kb = 0; kb < KOBS; kb += 32) {
        async_ld16(gA0 + kb, lA0);
        async_ld16(gA1 + kb, lA1);
        async_ld16(gB0 + kb, lB0);
        async_ld16(gB1 + kb, lB1);
        __syncthreads();

        bf16x8 af[4], bfx[4];
#pragma unroll
        for (int i = 0; i < 4; i++)    // A operand = W rows (n-dim)
            af[i] = *(const bf16x8*)&b_s[(wn + i * 16 + fr) * 32 + pcg * 8];
#pragma unroll
        for (int j = 0; j < 4; j++)    // B operand = x rows (t-dim)
            bfx[j] = *(const bf16x8*)&a_s[(wt + j * 16 + fr) * 32 + pcg * 8];

#pragma unroll
        for (int i = 0; i < 4; i++)
#pragma unroll
            for (int j = 0; j < 4; j++)
                acc[i][j] = __builtin_amdgcn_mfma_f32_16x16x32_bf16(
                    af[i], bfx[j], acc[i][j], 0, 0, 0);
        __syncthreads();
    }

    // ---- epilogue transpose: D row = wn+i*16+4*fq+reg (reg=proj),
    //      col = wt+j*16+fr.  planes: 0=bx 1=cc 2=la
    const int hq = wn >> 2;                  // 0 or 16
#pragma unroll
    for (int i = 0; i < 4; i++) {
        const int hl = hq + i * 4 + fq;      // h_local 0..31
        const float ae = A_e[bn * 32 + hl];
#pragma unroll
        for (int j = 0; j < 4; j++) {
            const int tl = wt + j * 16 + fr;
            f32x4 v = acc[i][j];
            float sig = 1.0f / (1.0f + __expf(-v[3]));
            smem[(0 * 128 + tl) * 40 + hl] = f2bf(v[0] * v[1]);  // BX
            smem[(1 * 128 + tl) * 40 + hl] = f2bf(v[2]);         // CC
            smem[(2 * 128 + tl) * 40 + hl] = f2bf(sig * ae);     // LA
        }
    }
    __syncthreads();

    // ---- pass1: seg totals + per-t (s_t, r_t) written in place
    {
        const int hi  = tid & 31;
        const int seg = tid >> 5;
        float p = 1.f, s = 0.f;
        const int tbase = seg * 16;
#pragma unroll
        for (int t = 0; t < 16; t++) {
            const int row = tbase + t;
            float a  = exp2f(bf2f(smem[(2 * 128 + row) * 40 + hi]));
            float bx = bf2f(smem[(0 * 128 + row) * 40 + hi]);
            s = fmaf(a, s, bx);
            p *= a;
            smem[(0 * 128 + row) * 40 + hi] = f2bf(s);   // local scan
            smem[(2 * 128 + row) * 40 + hi] = f2bf(p);   // local prefix-prod
        }
        Ps[seg * 32 + hi] = p;
        Ss[seg * 32 + hi] = s;
    }
    __syncthreads();

    // ---- seg-prefix in place; write chunk-level P,S
    if (tid < 32) {
        float rr = 1.f, sr = 0.f;
#pragma unroll
        for (int sg = 0; sg < 8; sg++) {
            float ps = Ps[sg * 32 + tid], ss = Ss[sg * 32 + tid];
            Ps[sg * 32 + tid] = rr;      // prefix product before seg
            Ss[sg * 32 + tid] = sr;      // local scan value at seg start
            sr = fmaf(ps, sr, ss);
            rr *= ps;
        }
        P[(size_t)bm * HID + bn * 32 + tid] = rr;
        S[(size_t)bm * HID + bn * 32 + tid] = sr;
    }
    __syncthreads();

    // ---- vectorized yb/yc: yc -> global (b128), yb -> plane0 (LDS)
#pragma unroll
    for (int it = 0; it < 2; it++) {
        const int idx = it * 256 + tid;      // 0..511
        const int t   = idx >> 2;
        const int cg  = idx & 3;
        const int sg  = t >> 4;
        u16x8 s8  = *(const u16x8*)&smem[(0 * 128 + t) * 40 + cg * 8];
        u16x8 r8  = *(const u16x8*)&smem[(2 * 128 + t) * 40 + cg * 8];
        u16x8 cc8 = *(const u16x8*)&smem[(1 * 128 + t) * 40 + cg * 8];
        u16x8 yb8, yc8;
#pragma unroll
        for (int e = 0; e < 8; e++) {
            float Sp = Ss[sg * 32 + cg * 8 + e];
            float Rp = Ps[sg * 32 + cg * 8 + e];
            float sv = bf2f(s8[e]);
            float rv = bf2f(r8[e]);
            float cc = bf2f(cc8[e]);
            yb8[e] = f2bf(cc * fmaf(rv, Sp, sv));
            yc8[e] = f2bf(cc * rv * Rp);
        }
        *(u16x8*)(YC + (size_t)(m0t + t) * HID + bn * 32 + cg * 8) = yc8;
        *(u16x8*)&smem[(0 * 128 + t) * 40 + cg * 8] = yb8;
    }
    __syncthreads();

    // ---- YB projection: A = W_out (8 o x 32 h), B = yb plane-0 frags;
    //      per-block bf16 partials, coalesced u16x4 stores (no atomics).
    bf16x8 wfrag = {0, 0, 0, 0, 0, 0, 0, 0};
    if (fr < 8) {
        const float* wp = W_out + (size_t)fr * HID + bn * 32 + fq * 8;
        float4 wa = *(const float4*)wp;
        float4 wb = *(const float4*)(wp + 4);
        wfrag[0] = (short)f2bf(wa.x); wfrag[1] = (short)f2bf(wa.y);
        wfrag[2] = (short)f2bf(wa.z); wfrag[3] = (short)f2bf(wa.w);
        wfrag[4] = (short)f2bf(wb.x); wfrag[5] = (short)f2bf(wb.y);
        wfrag[6] = (short)f2bf(wb.z); wfrag[7] = (short)f2bf(wb.w);
    }
#pragma unroll
    for (int mt = 0; mt < 2; mt++) {
        const int tb = wave * 32 + mt * 16;
        bf16x8 yfrag = *(const bf16x8*)&smem[(0 * 128 + tb + fr) * 40 + fq * 8];
        f32x4 pacc = {0.f, 0.f, 0.f, 0.f};
        pacc = __builtin_amdgcn_mfma_f32_16x16x32_bf16(wfrag, yfrag, pacc,
                                                       0, 0, 0);
        if (fq < 2) {
            u16x4 pv = { f2bf(pacc[0]), f2bf(pacc[1]),
                         f2bf(pacc[2]), f2bf(pacc[3]) };
            *(u16x4*)&Ptl16[((size_t)bn * TT + m0t + tb + fr) * NOBJ + 4 * fq]
                = pv;
        }
    }
}

// ---------------------------------------------------------------------------
// Kernel 3 (merged): blocks 0..7 = sequential combine -> H0;
// blocks 8..71 = reduce YB-projection bf16 partials over 64 bn groups and
// accumulate into out (atomic-free: each (t,o) owned by one thread; base
// already written by prep_all; coalesced u16x4 loads, float4 rmw stores).
// ---------------------------------------------------------------------------
__launch_bounds__(256)
__global__ void combine_reduce(const float* __restrict__ P,
                               const float* __restrict__ S,
                               float* __restrict__ H0,
                               const u16* __restrict__ Ptl16,
                               float* __restrict__ out)
{
    if (blockIdx.x < 8) {
        const int h = blockIdx.x * 256 + threadIdx.x;
        float hrun = 0.f;
#pragma unroll 8
        for (int c = 0; c < NCH; c++) {
            H0[c * HID + h] = hrun;
            hrun = fmaf(P[c * HID + h], hrun, S[c * HID + h]);
        }
    } else {
        const int rb = blockIdx.x - 8;                   // 0..63
        const int t  = rb * 128 + (threadIdx.x >> 1);    // 128 t per block
        const int q  = threadIdx.x & 1;                  // o-quad
        float sum0 = 0.f, sum1 = 0.f, sum2 = 0.f, sum3 = 0.f;
#pragma unroll 8
        for (int bn = 0; bn < 64; bn++) {
            u16x4 v = *(const u16x4*)
                &Ptl16[((size_t)bn * TT + t) * NOBJ + q * 4];
            sum0 += bf2f(v[0]); sum1 += bf2f(v[1]);
            sum2 += bf2f(v[2]); sum3 += bf2f(v[3]);
        }
        float4* op = (float4*)&out[(size_t)t * NOBJ + q * 4];
        float4 cur = *op;
        cur.x += sum0; cur.y += sum1; cur.z += sum2; cur.w += sum3;
        *op = cur;
    }
}

// ---------------------------------------------------------------------------
// Kernel 4: carried-state output: y[t,h] = YC * h0[chunk(t),h], then MFMA
// out-projection, atomicAdd into out (8 contenders per element).
// Block = (64-t sub-chunk, hgroup of 256 h): 1024 blocks.
// ---------------------------------------------------------------------------
__launch_bounds__(256)
__global__ void final_out(const u16* __restrict__ YC,
                          const float* __restrict__ H0,
                          const float* __restrict__ W_out,
                          float* __restrict__ out)
{
    __shared__ __align__(16) u16 ybuf[64 * 256];    // 32 KB
    __shared__ __align__(16) u16 wst[8 * 264];      // 4.2 KB
    __shared__ float h0s[256];
    const int tid  = threadIdx.x;
    const int tc   = blockIdx.x >> 3;    // 64-t sub-chunk, 0..127
    const int hg   = blockIdx.x & 7;
    const int lane = tid & 63;
    const int wave = tid >> 6;
    const int fr   = lane & 15;
    const int fq   = lane >> 4;
    const int t0   = tc * 64;

#pragma unroll
    for (int o = 0; o < 8; o++)
        wst[o * 264 + tid] = f2bf(W_out[(size_t)o * HID + hg * 256 + tid]);
    h0s[tid] = H0[(size_t)(tc >> 1) * HID + hg * 256 + tid];
    __syncthreads();

    // phase 1: y = yc*h0 -> ybuf (XOR-swizzled col groups)
    const int g   = tid & 31;            // h col-group (constant per thread)
    const int tb0 = tid >> 5;            // 0..7
    float4 h0a = *(const float4*)&h0s[g * 8];
    float4 h0b = *(const float4*)&h0s[g * 8 + 4];
    const float h0r[8] = { h0a.x, h0a.y, h0a.z, h0a.w,
                           h0b.x, h0b.y, h0b.z, h0b.w };
#pragma unroll
    for (int k = 0; k < 8; k++) {
        const int t = tb0 + k * 8;
        const size_t off = (size_t)(t0 + t) * HID + hg * 256 + g * 8;
        bf16x8 yc = *(const bf16x8*)(YC + off);
        bf16x8 yv;
#pragma unroll
        for (int e = 0; e < 8; e++)
            yv[e] = (short)f2bf(bf2f((u16)yc[e]) * h0r[e]);
        *(bf16x8*)&ybuf[t * 256 + ((g ^ (t & 7)) << 3)] = yv;
    }
    __syncthreads();

    // W_out A-frags from LDS: lane fr = o (rows 8..15 zero), k = fq*8+j
    bf16x8 bw[8];
#pragma unroll
    for (int ks = 0; ks < 8; ks++) {
        bf16x8 w = {0, 0, 0, 0, 0, 0, 0, 0};
        if (fr < 8)
            w = *(const bf16x8*)&wst[fr * 264 + ks * 32 + fq * 8];
        bw[ks] = w;
    }

    // phase 2: one 16-t m-tile per wave; D row (4fq+reg) = o, col fr = t
    {
        const int t = wave * 16 + fr;
        f32x4 acc2 = {0.f, 0.f, 0.f, 0.f};
#pragma unroll
        for (int ks = 0; ks < 8; ks++) {
            const int gg = ks * 4 + fq;
            bf16x8 yv = *(const bf16x8*)
                &ybuf[t * 256 + ((gg ^ (fr & 7)) << 3)];
            acc2 = __builtin_amdgcn_mfma_f32_16x16x32_bf16(bw[ks], yv, acc2,
                                                           0, 0, 0);
        }
        if (fq < 2) {
            const int tg = t0 + t;
#pragma unroll
            for (int reg = 0; reg < 4; reg++)
                atomicAdd(&out[(size_t)tg * NOBJ + 4 * fq + reg], acc2[reg]);
        }
    }
}

// ---------------------------------------------------------------------------
extern "C" void kernel_launch(void* const* d_in, const int* in_sizes, int n_in,
                              void* d_out, int out_size, void* d_ws, size_t ws_size,
                              hipStream_t stream)
{
    const float* x      = (const float*)d_in[0];
    const float* Win    = (const float*)d_in[1];
    const float* WB     = (const float*)d_in[2];
    const float* WC     = (const float*)d_in[3];
    const float* Wd     = (const float*)d_in[4];
    const float* A_log  = (const float*)d_in[5];
    const float* W_out  = (const float*)d_in[6];
    const float* b_out  = (const float*)d_in[7];
    const float* W_skip = (const float*)d_in[8];
    float* out = (float*)d_out;

    char* ws = (char*)d_ws;
    size_t off = 0;
    auto alloc = [&](size_t bytes) -> void* {
        void* p = (void*)(ws + off);
        off += (bytes + 255) & ~(size_t)255;
        return p;
    };

    u16*   x_bf  = (u16*)  alloc((size_t)TT * KOBS * 2);        //  8.4 MB
    u16*   W_bf  = (u16*)  alloc((size_t)4 * HID * KOBS * 2);   //  8.4 MB
    float* A_e   = (float*)alloc((size_t)HID * 4);
    u16*   YC    = (u16*)  alloc((size_t)TT * HID * 2);         // 33.6 MB
    u16*   Ptl16 = (u16*)  alloc((size_t)64 * TT * NOBJ * 2);   //  8.4 MB
    float* P     = (float*)alloc((size_t)NCH * HID * 4);        //  0.5 MB
    float* S     = (float*)alloc((size_t)NCH * HID * 4);        //  0.5 MB
    float* H0    = (float*)alloc((size_t)NCH * HID * 4);        //  0.5 MB
    (void)ws_size; (void)in_sizes; (void)n_in; (void)out_size;  // ~60.3 MB

    prep_all<<<1536, 256, 0, stream>>>(x, Win, WB, WC, Wd, A_log,
                                       b_out, W_skip, out, x_bf, W_bf, A_e);
    gemm_fused<<<4096, 256, 0, stream>>>(x_bf, W_bf, A_e, W_out,
                                         YC, Ptl16, P, S);
    combine_reduce<<<72, 256, 0, stream>>>(P, S, H0, Ptl16, out);
    final_out<<<1024, 256, 0, stream>>>(YC, H0, W_out, out);
}

// Round 12
// 193.234 us; speedup vs baseline: 1.0715x; 1.0715x over previous
//
#include <hip/hip_runtime.h>
#include <hip/hip_bf16.h>
#include <cstdint>

#define TT   8192
#define KOBS 512
#define HID  2048
#define NOBJ 8
#define NCH  64     // number of scan chunks (= gemm t-tiles)
#define CT   128    // chunk length (TT / NCH)

typedef unsigned short u16;
typedef uint32_t u32;
typedef short bf16x8 __attribute__((ext_vector_type(8)));
typedef float f32x4  __attribute__((ext_vector_type(4)));
typedef unsigned short u16x4 __attribute__((ext_vector_type(4)));
typedef unsigned short u16x8 __attribute__((ext_vector_type(8)));

static __device__ __forceinline__ float bf2f(u16 u) {
    union { uint32_t i; float f; } v;
    v.i = ((uint32_t)u) << 16;
    return v.f;
}
static __device__ __forceinline__ u16 f2bf(float f) {
    union { float f; uint32_t i; } v;
    v.f = f;
    uint32_t lsb = (v.i >> 16) & 1u;
    uint32_t r = v.i + 0x7fffu + lsb;   // round-to-nearest-even
    return (u16)(r >> 16);
}

// async global->LDS DMA, 16 bytes per lane (wave-uniform base + lane*16).
static __device__ __forceinline__ void async_ld16(const u16* g, u16* l) {
    __builtin_amdgcn_global_load_lds(
        (const __attribute__((address_space(1))) uint32_t*)g,
        (__attribute__((address_space(3))) uint32_t*)l,
        16, 0, 0);
}

// ---------------------------------------------------------------------------
// Kernel 1 (merged prep):
//  blocks [0,512):    out base = b_out + x @ W_skip.T; x -> bf16 cast
//  blocks [512,1536): W cast + row-interleave (row n = 4h+proj); A_e
// ---------------------------------------------------------------------------
__launch_bounds__(256)
__global__ void prep_all(const float* __restrict__ x,
                         const float* __restrict__ Win,
                         const float* __restrict__ WB,
                         const float* __restrict__ WC,
                         const float* __restrict__ Wd,
                         const float* __restrict__ A_log,
                         const float* __restrict__ b_out,
                         const float* __restrict__ W_skip,
                         float* __restrict__ out,
                         u16* __restrict__ x_bf,
                         u16* __restrict__ W_bf,
                         float* __restrict__ A_e)
{
    if (blockIdx.x < 512) {
        const int wave = threadIdx.x >> 6;
        const int lane = threadIdx.x & 63;
        const int t0 = (blockIdx.x * 4 + wave) * 4;

        float acc[4][NOBJ];
#pragma unroll
        for (int tt = 0; tt < 4; tt++)
#pragma unroll
            for (int o = 0; o < NOBJ; o++) acc[tt][o] = 0.f;

#pragma unroll
        for (int i = 0; i < 2; i++) {
            const int kv = (i * 64 + lane) * 4;
            float4 w[NOBJ];
#pragma unroll
            for (int o = 0; o < NOBJ; o++)
                w[o] = *(const float4*)(W_skip + (size_t)o * KOBS + kv);
#pragma unroll
            for (int tt = 0; tt < 4; tt++) {
                const size_t off = (size_t)(t0 + tt) * KOBS + kv;
                float4 xv = *(const float4*)(x + off);
                u16x4 xb = { f2bf(xv.x), f2bf(xv.y), f2bf(xv.z), f2bf(xv.w) };
                *(u16x4*)&x_bf[off] = xb;
#pragma unroll
                for (int o = 0; o < NOBJ; o++)
                    acc[tt][o] += xv.x * w[o].x + xv.y * w[o].y +
                                  xv.z * w[o].z + xv.w * w[o].w;
            }
        }
#pragma unroll
        for (int s = 32; s > 0; s >>= 1)
#pragma unroll
            for (int tt = 0; tt < 4; tt++)
#pragma unroll
                for (int o = 0; o < NOBJ; o++)
                    acc[tt][o] += __shfl_xor(acc[tt][o], s, 64);
        if (lane == 0) {
#pragma unroll
            for (int tt = 0; tt < 4; tt++)
#pragma unroll
                for (int o = 0; o < NOBJ; o++)
                    out[(size_t)(t0 + tt) * NOBJ + o] = acc[tt][o] + b_out[o];
        }
    } else {
        const int tid0 = (blockIdx.x - 512) * 256 + threadIdx.x; // 0..262143
#pragma unroll
        for (int q = 0; q < 2; q++) {
            const int i = tid0 + q * 262144;     // group of 8 elems
            int n  = i >> 6;
            int k8 = (i & 63) * 8;
            int h  = n >> 2;
            int w  = n & 3;
            const float* src = (w == 0) ? Win : (w == 1) ? WB
                             : (w == 2) ? WC  : Wd;
            const float4* s4 = (const float4*)(src + (size_t)h * KOBS + k8);
            float4 a = s4[0], b = s4[1];
            u16x4 o1 = { f2bf(a.x), f2bf(a.y), f2bf(a.z), f2bf(a.w) };
            u16x4 o2 = { f2bf(b.x), f2bf(b.y), f2bf(b.z), f2bf(b.w) };
            *(u16x4*)&W_bf[(size_t)i * 8]     = o1;
            *(u16x4*)&W_bf[(size_t)i * 8 + 4] = o2;
        }
        if (tid0 < HID)
            A_e[tid0] = -__expf(A_log[tid0]) * 1.44269504f;
    }
}

// ---------------------------------------------------------------------------
// Kernel 2: fused GEMM + elementwise + in-LDS chunk scan + YB projection.
// BK=64: 8 K-iters, 16 barriers (halved), 32 MFMAs between barriers.
// LDS: staging 2 x [128][64] bf16 = 32 KB, union epilogue 30 KB; +2 KB
// Ps/Ss = 34.8 KB -> 4 blocks/CU (same as BK=32 -> barrier cut is free).
// Swizzle (row stride = 8 bank-quads): phys_cg = cg ^ (row&7); 16-row
// b128 frag reads cover all 8 quads twice = 2-way = free.
// 8x8 supertile block order for L2 locality (2 MB working set / 64 blocks).
// ---------------------------------------------------------------------------
__launch_bounds__(256, 6)
__global__ void gemm_fused(const u16* __restrict__ x_bf,
                           const u16* __restrict__ W_bf,
                           const float* __restrict__ A_e,
                           const float* __restrict__ W_out,
                           u16* __restrict__ YC,
                           u16* __restrict__ Ptl16,
                           float* __restrict__ P,
                           float* __restrict__ S)
{
    __shared__ __align__(16) u16 smem[16384];          // 32 KB (union)
    __shared__ float Ps[256], Ss[256];                 //  2 KB
    u16* a_s = smem;            // x tile: 128 t-rows x 64 k
    u16* b_s = smem + 8192;     // W tile: 128 n-rows x 64 k

    const int tid  = threadIdx.x;
    // 8x8 supertile swizzle of the 64x64 (bm,bn) grid
    const int sg   = blockIdx.x >> 6;
    const int wi   = blockIdx.x & 63;
    const int bm   = (sg & 7) * 8 + (wi & 7);    // t-chunk (== scan chunk c)
    const int bn   = (sg >> 3) * 8 + (wi >> 3);  // channel group (32 h)
    const int m0t  = bm * 128;
    const int n0   = bn * 128;
    const int lane = tid & 63;
    const int wave = tid >> 6;
    const int wn   = (wave & 1) * 64;    // n-dim wave offset
    const int wt   = (wave >> 1) * 64;   // t-dim wave offset
    const int fr   = lane & 15;
    const int fq   = lane >> 4;

    f32x4 acc[4][4];
#pragma unroll
    for (int i = 0; i < 4; i++)
#pragma unroll
        for (int j = 0; j < 4; j++) {
            f32x4 z = {0.f, 0.f, 0.f, 0.f};
            acc[i][j] = z;
        }

    // staging: pass p (0..3) covers rows p*32 + (tid>>3), col-group
    // scg = (tid&7) ^ ((tid>>3)&7)  (XOR swizzle, row&7 == (tid>>3)&7)
    const int srow8 = tid >> 3;                      // 0..31
    const int scg   = (tid & 7) ^ (srow8 & 7);
    const u16* gA = x_bf + (size_t)(m0t + srow8) * KOBS + scg * 8;
    const u16* gB = W_bf + (size_t)(n0 + srow8) * KOBS + scg * 8;
    u16* lA = &a_s[tid * 8];
    u16* lB = &b_s[tid * 8];

    for (int kb = 0; kb < KOBS; kb += 64) {
#pragma unroll
        for (int p = 0; p < 4; p++) {
            async_ld16(gA + (size_t)p * 32 * KOBS + kb, lA + p * 2048);
            async_ld16(gB + (size_t)p * 32 * KOBS + kb, lB + p * 2048);
        }
        __syncthreads();

#pragma unroll
        for (int ks = 0; ks < 2; ks++) {
            const int pcg = (ks * 4 + fq) ^ (fr & 7);
            bf16x8 af[4], bfx[4];
#pragma unroll
            for (int i = 0; i < 4; i++)    // A operand = W rows (n-dim)
                af[i] = *(const bf16x8*)&b_s[(wn + i * 16 + fr) * 64 + pcg * 8];
#pragma unroll
            for (int j = 0; j < 4; j++)    // B operand = x rows (t-dim)
                bfx[j] = *(const bf16x8*)&a_s[(wt + j * 16 + fr) * 64 + pcg * 8];

#pragma unroll
            for (int i = 0; i < 4; i++)
#pragma unroll
                for (int j = 0; j < 4; j++)
                    acc[i][j] = __builtin_amdgcn_mfma_f32_16x16x32_bf16(
                        af[i], bfx[j], acc[i][j], 0, 0, 0);
        }
        __syncthreads();
    }

    // ---- epilogue transpose: D row = wn+i*16+4*fq+reg (reg=proj),
    //      col = wt+j*16+fr.  planes: 0=bx 1=cc 2=la  (stride 40)
    const int hq = wn >> 2;                  // 0 or 16
#pragma unroll
    for (int i = 0; i < 4; i++) {
        const int hl = hq + i * 4 + fq;      // h_local 0..31
        const float ae = A_e[bn * 32 + hl];
#pragma unroll
        for (int j = 0; j < 4; j++) {
            const int tl = wt + j * 16 + fr;
            f32x4 v = acc[i][j];
            float sig = 1.0f / (1.0f + __expf(-v[3]));
            smem[(0 * 128 + tl) * 40 + hl] = f2bf(v[0] * v[1]);  // BX
            smem[(1 * 128 + tl) * 40 + hl] = f2bf(v[2]);         // CC
            smem[(2 * 128 + tl) * 40 + hl] = f2bf(sig * ae);     // LA
        }
    }
    __syncthreads();

    // ---- pass1: seg totals + per-t (s_t, r_t) written in place
    {
        const int hi  = tid & 31;
        const int seg = tid >> 5;
        float p = 1.f, s = 0.f;
        const int tbase = seg * 16;
#pragma unroll
        for (int t = 0; t < 16; t++) {
            const int row = tbase + t;
            float a  = exp2f(bf2f(smem[(2 * 128 + row) * 40 + hi]));
            float bx = bf2f(smem[(0 * 128 + row) * 40 + hi]);
            s = fmaf(a, s, bx);
            p *= a;
            smem[(0 * 128 + row) * 40 + hi] = f2bf(s);   // local scan
            smem[(2 * 128 + row) * 40 + hi] = f2bf(p);   // local prefix-prod
        }
        Ps[seg * 32 + hi] = p;
        Ss[seg * 32 + hi] = s;
    }
    __syncthreads();

    // ---- seg-prefix in place; write chunk-level P,S
    if (tid < 32) {
        float rr = 1.f, sr = 0.f;
#pragma unroll
        for (int sgg = 0; sgg < 8; sgg++) {
            float ps = Ps[sgg * 32 + tid], ss = Ss[sgg * 32 + tid];
            Ps[sgg * 32 + tid] = rr;     // prefix product before seg
            Ss[sgg * 32 + tid] = sr;     // local scan value at seg start
            sr = fmaf(ps, sr, ss);
            rr *= ps;
        }
        P[(size_t)bm * HID + bn * 32 + tid] = rr;
        S[(size_t)bm * HID + bn * 32 + tid] = sr;
    }
    __syncthreads();

    // ---- vectorized yb/yc: yc -> global (b128), yb -> plane0 (LDS)
#pragma unroll
    for (int it = 0; it < 2; it++) {
        const int idx = it * 256 + tid;      // 0..511
        const int t   = idx >> 2;
        const int cg  = idx & 3;
        const int sgg = t >> 4;
        u16x8 s8  = *(const u16x8*)&smem[(0 * 128 + t) * 40 + cg * 8];
        u16x8 r8  = *(const u16x8*)&smem[(2 * 128 + t) * 40 + cg * 8];
        u16x8 cc8 = *(const u16x8*)&smem[(1 * 128 + t) * 40 + cg * 8];
        u16x8 yb8, yc8;
#pragma unroll
        for (int e = 0; e < 8; e++) {
            float Sp = Ss[sgg * 32 + cg * 8 + e];
            float Rp = Ps[sgg * 32 + cg * 8 + e];
            float sv = bf2f(s8[e]);
            float rv = bf2f(r8[e]);
            float cc = bf2f(cc8[e]);
            yb8[e] = f2bf(cc * fmaf(rv, Sp, sv));
            yc8[e] = f2bf(cc * rv * Rp);
        }
        *(u16x8*)(YC + (size_t)(m0t + t) * HID + bn * 32 + cg * 8) = yc8;
        *(u16x8*)&smem[(0 * 128 + t) * 40 + cg * 8] = yb8;
    }
    __syncthreads();

    // ---- YB projection: A = W_out (8 o x 32 h), B = yb plane-0 frags;
    //      per-block bf16 partials, coalesced u16x4 stores (no atomics).
    bf16x8 wfrag = {0, 0, 0, 0, 0, 0, 0, 0};
    if (fr < 8) {
        const float* wp = W_out + (size_t)fr * HID + bn * 32 + fq * 8;
        float4 wa = *(const float4*)wp;
        float4 wb = *(const float4*)(wp + 4);
        wfrag[0] = (short)f2bf(wa.x); wfrag[1] = (short)f2bf(wa.y);
        wfrag[2] = (short)f2bf(wa.z); wfrag[3] = (short)f2bf(wa.w);
        wfrag[4] = (short)f2bf(wb.x); wfrag[5] = (short)f2bf(wb.y);
        wfrag[6] = (short)f2bf(wb.z); wfrag[7] = (short)f2bf(wb.w);
    }
#pragma unroll
    for (int mt = 0; mt < 2; mt++) {
        const int tb = wave * 32 + mt * 16;
        bf16x8 yfrag = *(const bf16x8*)&smem[(0 * 128 + tb + fr) * 40 + fq * 8];
        f32x4 pacc = {0.f, 0.f, 0.f, 0.f};
        pacc = __builtin_amdgcn_mfma_f32_16x16x32_bf16(wfrag, yfrag, pacc,
                                                       0, 0, 0);
        if (fq < 2) {
            u16x4 pv = { f2bf(pacc[0]), f2bf(pacc[1]),
                         f2bf(pacc[2]), f2bf(pacc[3]) };
            *(u16x4*)&Ptl16[((size_t)bn * TT + m0t + tb + fr) * NOBJ + 4 * fq]
                = pv;
        }
    }
}

// ---------------------------------------------------------------------------
// Kernel 3 (merged): blocks 0..7 = sequential combine -> H0;
// blocks 8..71 = reduce YB-projection bf16 partials over 64 bn groups and
// accumulate into out (atomic-free; base already written by prep_all).
// ---------------------------------------------------------------------------
__launch_bounds__(256)
__global__ void combine_reduce(const float* __restrict__ P,
                               const float* __restrict__ S,
                               float* __restrict__ H0,
                               const u16* __restrict__ Ptl16,
                               float* __restrict__ out)
{
    if (blockIdx.x < 8) {
        const int h = blockIdx.x * 256 + threadIdx.x;
        float hrun = 0.f;
#pragma unroll 8
        for (int c = 0; c < NCH; c++) {
            H0[c * HID + h] = hrun;
            hrun = fmaf(P[c * HID + h], hrun, S[c * HID + h]);
        }
    } else {
        const int rb = blockIdx.x - 8;                   // 0..63
        const int t  = rb * 128 + (threadIdx.x >> 1);    // 128 t per block
        const int q  = threadIdx.x & 1;                  // o-quad
        float sum0 = 0.f, sum1 = 0.f, sum2 = 0.f, sum3 = 0.f;
#pragma unroll 8
        for (int bn = 0; bn < 64; bn++) {
            u16x4 v = *(const u16x4*)
                &Ptl16[((size_t)bn * TT + t) * NOBJ + q * 4];
            sum0 += bf2f(v[0]); sum1 += bf2f(v[1]);
            sum2 += bf2f(v[2]); sum3 += bf2f(v[3]);
        }
        float4* op = (float4*)&out[(size_t)t * NOBJ + q * 4];
        float4 cur = *op;
        cur.x += sum0; cur.y += sum1; cur.z += sum2; cur.w += sum3;
        *op = cur;
    }
}

// ---------------------------------------------------------------------------
// Kernel 4: carried-state output: y[t,h] = YC * h0[chunk(t),h], then MFMA
// out-projection, atomicAdd into out (8 contenders per element).
// Block = (64-t sub-chunk, hgroup of 256 h): 1024 blocks.
// ---------------------------------------------------------------------------
__launch_bounds__(256)
__global__ void final_out(const u16* __restrict__ YC,
                          const float* __restrict__ H0,
                          const float* __restrict__ W_out,
                          float* __restrict__ out)
{
    __shared__ __align__(16) u16 ybuf[64 * 256];    // 32 KB
    __shared__ __align__(16) u16 wst[8 * 264];      // 4.2 KB
    __shared__ float h0s[256];
    const int tid  = threadIdx.x;
    const int tc   = blockIdx.x >> 3;    // 64-t sub-chunk, 0..127
    const int hg   = blockIdx.x & 7;
    const int lane = tid & 63;
    const int wave = tid >> 6;
    const int fr   = lane & 15;
    const int fq   = lane >> 4;
    const int t0   = tc * 64;

#pragma unroll
    for (int o = 0; o < 8; o++)
        wst[o * 264 + tid] = f2bf(W_out[(size_t)o * HID + hg * 256 + tid]);
    h0s[tid] = H0[(size_t)(tc >> 1) * HID + hg * 256 + tid];
    __syncthreads();

    // phase 1: y = yc*h0 -> ybuf (XOR-swizzled col groups)
    const int g   = tid & 31;            // h col-group (constant per thread)
    const int tb0 = tid >> 5;            // 0..7
    float4 h0a = *(const float4*)&h0s[g * 8];
    float4 h0b = *(const float4*)&h0s[g * 8 + 4];
    const float h0r[8] = { h0a.x, h0a.y, h0a.z, h0a.w,
                           h0b.x, h0b.y, h0b.z, h0b.w };
#pragma unroll
    for (int k = 0; k < 8; k++) {
        const int t = tb0 + k * 8;
        const size_t off = (size_t)(t0 + t) * HID + hg * 256 + g * 8;
        bf16x8 yc = *(const bf16x8*)(YC + off);
        bf16x8 yv;
#pragma unroll
        for (int e = 0; e < 8; e++)
            yv[e] = (short)f2bf(bf2f((u16)yc[e]) * h0r[e]);
        *(bf16x8*)&ybuf[t * 256 + ((g ^ (t & 7)) << 3)] = yv;
    }
    __syncthreads();

    // W_out A-frags from LDS: lane fr = o (rows 8..15 zero), k = fq*8+j
    bf16x8 bw[8];
#pragma unroll
    for (int ks = 0; ks < 8; ks++) {
        bf16x8 w = {0, 0, 0, 0, 0, 0, 0, 0};
        if (fr < 8)
            w = *(const bf16x8*)&wst[fr * 264 + ks * 32 + fq * 8];
        bw[ks] = w;
    }

    // phase 2: one 16-t m-tile per wave; D row (4fq+reg) = o, col fr = t
    {
        const int t = wave * 16 + fr;
        f32x4 acc2 = {0.f, 0.f, 0.f, 0.f};
#pragma unroll
        for (int ks = 0; ks < 8; ks++) {
            const int gg = ks * 4 + fq;
            bf16x8 yv = *(const bf16x8*)
                &ybuf[t * 256 + ((gg ^ (fr & 7)) << 3)];
            acc2 = __builtin_amdgcn_mfma_f32_16x16x32_bf16(bw[ks], yv, acc2,
                                                           0, 0, 0);
        }
        if (fq < 2) {
            const int tg = t0 + t;
#pragma unroll
            for (int reg = 0; reg < 4; reg++)
                atomicAdd(&out[(size_t)tg * NOBJ + 4 * fq + reg], acc2[reg]);
        }
    }
}

// ---------------------------------------------------------------------------
extern "C" void kernel_launch(void* const* d_in, const int* in_sizes, int n_in,
                              void* d_out, int out_size, void* d_ws, size_t ws_size,
                              hipStream_t stream)
{
    const float* x      = (const float*)d_in[0];
    const float* Win    = (const float*)d_in[1];
    const float* WB     = (const float*)d_in[2];
    const float* WC     = (const float*)d_in[3];
    const float* Wd     = (const float*)d_in[4];
    const float* A_log  = (const float*)d_in[5];
    const float* W_out  = (const float*)d_in[6];
    const float* b_out  = (const float*)d_in[7];
    const float* W_skip = (const float*)d_in[8];
    float* out = (float*)d_out;

    char* ws = (char*)d_ws;
    size_t off = 0;
    auto alloc = [&](size_t bytes) -> void* {
        void* p = (void*)(ws + off);
        off += (bytes + 255) & ~(size_t)255;
        return p;
    };

    u16*   x_bf  = (u16*)  alloc((size_t)TT * KOBS * 2);        //  8.4 MB
    u16*   W_bf  = (u16*)  alloc((size_t)4 * HID * KOBS * 2);   //  8.4 MB
    float* A_e   = (float*)alloc((size_t)HID * 4);
    u16*   YC    = (u16*)  alloc((size_t)TT * HID * 2);         // 33.6 MB
    u16*   Ptl16 = (u16*)  alloc((size_t)64 * TT * NOBJ * 2);   //  8.4 MB
    float* P     = (float*)alloc((size_t)NCH * HID * 4);        //  0.5 MB
    float* S     = (float*)alloc((size_t)NCH * HID * 4);        //  0.5 MB
    float* H0    = (float*)alloc((size_t)NCH * HID * 4);        //  0.5 MB
    (void)ws_size; (void)in_sizes; (void)n_in; (void)out_size;  // ~60.3 MB

    prep_all<<<1536, 256, 0, stream>>>(x, Win, WB, WC, Wd, A_log,
                                       b_out, W_skip, out, x_bf, W_bf, A_e);
    gemm_fused<<<4096, 256, 0, stream>>>(x_bf, W_bf, A_e, W_out,
                                         YC, Ptl16, P, S);
    combine_reduce<<<72, 256, 0, stream>>>(P, S, H0, Ptl16, out);
    final_out<<<1024, 256, 0, stream>>>(YC, H0, W_out, out);
}